// Round 10
// baseline (635.246 us; speedup 1.0000x reference)
//
#include <hip/hip_runtime.h>

#define N_ROWS   131072
#define D_IN     512
#define D_H      128
#define K_CODES  256
#define NT       1024         // 16 waves, 16 rows each
#define PNT      256          // prep/finalize block size (layout-coupled)
#define RPB      256          // rows per block
#define NBLK     (N_ROWS / RPB)   // 512 -> 1 block/CU, 2 generations, 7 rounds each
#define SA       136          // s_A row stride in bf16 elems (272 B, breaks power-of-2)

typedef __attribute__((ext_vector_type(8))) short bf16x8;
typedef __attribute__((ext_vector_type(4))) float f32x4;

__device__ inline unsigned short f2bf(float f) {
    unsigned u = __float_as_uint(f);
    return (unsigned short)((u + 0x7FFFu + ((u >> 16) & 1u)) >> 16);
}
__device__ inline ushort4 f2bf4(float4 v) {
    return make_ushort4(f2bf(v.x), f2bf(v.y), f2bf(v.z), f2bf(v.w));
}
__device__ inline bf16x8 f2bf8(float4 a, float4 b) {
    bf16x8 r;
    r[0] = (short)f2bf(a.x); r[1] = (short)f2bf(a.y); r[2] = (short)f2bf(a.z); r[3] = (short)f2bf(a.w);
    r[4] = (short)f2bf(b.x); r[5] = (short)f2bf(b.y); r[6] = (short)f2bf(b.z); r[7] = (short)f2bf(b.w);
    return r;
}

// ---------------- prep: reorder weights/codebooks into MFMA B-fragment order ----------------
// frag(ct,ks): lane = qd*16+nn holds B[n=ct*16+nn][k=ks*32+qd*8+j], j=0..7. 32KB round = 8ct x 4ks.
// wsb (ushorts): [0..65535] Wenc (kc=0..3) | [65536..163839] cb (t,half) | [163840..229375] Wdec (c=0..3)
__global__ void rqvae_prep(const float* __restrict__ Wenc,
                           const float* __restrict__ Wdec,
                           const float* __restrict__ cb0,
                           const float* __restrict__ cb1,
                           const float* __restrict__ cb2,
                           unsigned short* __restrict__ wsb,
                           float* __restrict__ norms)
{
    const int tid = threadIdx.x;
    const int b = blockIdx.x;
    const float* cbs[3] = {cb0, cb1, cb2};
    if (b < 112) {
        const int g = b * 256 + tid;            // ushort8 group id, 0..28671
        const int lane = g & 63, ks = (g >> 6) & 3, ct = (g >> 8) & 7;
        const int nn = lane & 15, qd = lane >> 4;
        const float* src;
        if (g < 8192) {                         // Wenc: kc = g>>11
            const int kc = g >> 11;
            src = Wenc + (ct * 16 + nn) * D_IN + kc * 128 + ks * 32 + qd * 8;
        } else if (g < 20480) {                 // cb: t = (g-8192)>>12, half = bit 11
            const int r = g - 8192;
            const int t = r >> 12, half = (r >> 11) & 1;
            src = cbs[t] + (long)(half * 128 + ct * 16 + nn) * D_H + ks * 32 + qd * 8;
        } else {                                // Wdec: c = (g-20480)>>11
            const int r = g - 20480;
            const int c = r >> 11;
            src = Wdec + (long)(c * 128 + ct * 16 + nn) * D_H + ks * 32 + qd * 8;
        }
        float4 v0 = *(const float4*)(src);
        float4 v1 = *(const float4*)(src + 4);
        *(ushort4*)(wsb + (long)g * 8)     = f2bf4(v0);
        *(ushort4*)(wsb + (long)g * 8 + 4) = f2bf4(v1);
    } else {
        const int t = b - 112;                  // norm blocks: one code per thread
        const float4* r = (const float4*)(cbs[t] + (long)tid * D_H);
        float s = 0.f;
        #pragma unroll
        for (int d = 0; d < 32; ++d) { float4 v = r[d]; s += v.x*v.x + v.y*v.y + v.z*v.z + v.w*v.w; }
        norms[t * K_CODES + tid] = -0.5f * s;
    }
}

// ---------------- main ----------------
// SLOT-MINIMIZED geometry. Serial staging slots per CU = NBLK*R/(256*C) was 28
// in EVERY prior variant (~10us/slot = the invariant 280us). This config is the
// LDS-cap corner that minimizes slots: RPB=256, s_B=64KB, C=1, NT=1024
// (s_A 69.6KB + s_B 64KB + cn 3KB = 138KB). Rounds/block: 2 (Wenc, 64KB chunks,
// A direct global->reg) + 3 (ONE full codebook per round; argmax scans all 256
// codes in one slot) + 2 (Wdec) = 7 -> slots = 512*7/256 = 14, HALF the champion.
// Also 16 waves/CU (4/SIMD, 2x champion TLP) with slim state: rem[8]=32 acc regs,
// res re-gathered from saved indices (round-5-proven bit-exact chain).
__global__ __launch_bounds__(NT, 4) void rqvae_main(
    const float* __restrict__ emb,
    const float* __restrict__ cb0,
    const float* __restrict__ cb1,
    const float* __restrict__ cb2,
    const unsigned short* __restrict__ wsb,
    const float* __restrict__ norms,
    float* __restrict__ acc_rq,
    float* __restrict__ acc_recon,
    int* __restrict__ used)
{
    __shared__ unsigned short s_A[RPB * SA];   // 69632 B: latent/rem/restored, wave-private 16-row slices
    __shared__ unsigned short s_B[32768];      // 65536 B: one 64KB B chunk, fragment-linear
    __shared__ float s_cn[3 * K_CODES];        // 3072 B  -> total 138240 B, 1 block/CU

    const int tid  = threadIdx.x;
    const int wv   = tid >> 6;                 // 0..15
    const int lane = tid & 63;
    const int nn   = lane & 15;
    const int qd   = lane >> 4;
    const int wrow = wv * 16;                  // this wave's 16 rows
    const long blkRow = (long)blockIdx.x * RPB;

    for (int i = tid; i < 3 * K_CODES; i += NT) s_cn[i] = norms[i];

    // stage one 64KB chunk (= two legacy 32KB rounds), linear: 4 x 16B per thread
#define COPY64(srcbase) do {                                                    \
        const bf16x8* _s = (const bf16x8*)(srcbase);                            \
        bf16x8* _d = (bf16x8*)s_B;                                              \
        _Pragma("unroll")                                                       \
        for (int _i = 0; _i < 4; ++_i) _d[tid + _i * NT] = _s[tid + _i * NT];   \
    } while (0)

    f32x4 rem[8];
    #pragma unroll
    for (int ct = 0; ct < 8; ++ct) rem[ct] = {0.f,0.f,0.f,0.f};

    // ---- Phase 1: latent = emb @ Wenc^T; 2 x 64KB chunks, A direct global->reg ----
    #pragma unroll 1
    for (int r1 = 0; r1 < 2; ++r1) {
        __syncthreads();
        COPY64(wsb + r1 * 32768);
        __syncthreads();
        #pragma unroll 1
        for (int kh = 0; kh < 2; ++kh) {
            const int kc = r1 * 2 + kh;        // K chunk 0..3, natural order
            const float* ar = emb + (blkRow + wrow + nn) * D_IN + kc * 128 + qd * 8;
            bf16x8 af[4];
            #pragma unroll
            for (int ks = 0; ks < 4; ++ks)
                af[ks] = f2bf8(*(const float4*)(ar + ks * 32), *(const float4*)(ar + ks * 32 + 4));
            #pragma unroll
            for (int ct = 0; ct < 8; ++ct)
                #pragma unroll
                for (int ks = 0; ks < 4; ++ks) {
                    bf16x8 bf = *(const bf16x8*)&s_B[kh * 16384 + (ct * 4 + ks) * 512 + lane * 8];
                    rem[ct] = __builtin_amdgcn_mfma_f32_16x16x32_bf16(af[ks], bf, rem[ct], 0, 0, 0);
                }
        }
    }

    // latent -> s_A bf16 (wave-private rows)
    #pragma unroll
    for (int ct = 0; ct < 8; ++ct)
        #pragma unroll
        for (int e = 0; e < 4; ++e)
            s_A[(wrow + qd * 4 + e) * SA + ct * 16 + nn] = f2bf(rem[ct][e]);

    // ---- Phase 2: three RQ stages; ONE 64KB round per stage (all 256 codes) ----
    float local_rq = 0.f;
    int bis0[4], bis1[4], bis2[4];
    #pragma unroll 1
    for (int t = 0; t < 3; ++t) {
        const float* __restrict__ cb = (t == 0) ? cb0 : ((t == 1) ? cb1 : cb2);
        float bv[4]; int bi[4];
        #pragma unroll
        for (int e = 0; e < 4; ++e) { bv[e] = -3.402823466e38f; bi[e] = 0; }

        bf16x8 af[4];
        #pragma unroll
        for (int ks = 0; ks < 4; ++ks)
            af[ks] = *(const bf16x8*)&s_A[(wrow + nn) * SA + ks * 32 + qd * 8];

        __syncthreads();
        COPY64(wsb + 65536 + t * 32768);
        __syncthreads();
        #pragma unroll 2
        for (int ctc = 0; ctc < 16; ++ctc) {
            f32x4 s = {0.f,0.f,0.f,0.f};
            #pragma unroll
            for (int ks = 0; ks < 4; ++ks) {
                bf16x8 bf = *(const bf16x8*)&s_B[(ctc * 4 + ks) * 512 + lane * 8];
                s = __builtin_amdgcn_mfma_f32_16x16x32_bf16(af[ks], bf, s, 0, 0, 0);
            }
            const int code = ctc * 16 + nn;    // == (ctc>>3)*128 + (ctc&7)*16 + nn
            const float cn = s_cn[t * K_CODES + code];
            #pragma unroll
            for (int e = 0; e < 4; ++e) {
                const float v = s[e] + cn;
                if (v > bv[e] || (v == bv[e] && code < bi[e])) { bv[e] = v; bi[e] = code; }
            }
        }
        // argmax over the 16 nn-lanes of each quad (tie -> lowest index)
        #pragma unroll
        for (int e = 0; e < 4; ++e) {
            float v = bv[e]; int i0 = bi[e];
            #pragma unroll
            for (int m = 8; m >= 1; m >>= 1) {
                const float ov = __shfl_xor(v, m);
                const int   oi = __shfl_xor(i0, m);
                if (ov > v || (ov == v && oi < i0)) { v = ov; i0 = oi; }
            }
            bi[e] = i0;
            if (t == 0) bis0[e] = i0; else if (t == 1) bis1[e] = i0; else bis2[e] = i0;
            if (nn == 0) used[t * K_CODES + i0] = 1;
        }
        // rem update with fp32 codebook rows (res re-gathered later)
        #pragma unroll
        for (int ct = 0; ct < 8; ++ct)
            #pragma unroll
            for (int e = 0; e < 4; ++e) {
                const float c = cb[(long)bi[e] * D_H + ct * 16 + nn];
                const float rr = rem[ct][e] - c;
                rem[ct][e] = rr;
                local_rq += rr * rr;
                if (t < 2)
                    s_A[(wrow + qd * 4 + e) * SA + ct * 16 + nn] = f2bf(rr);
            }
    }

    // restored = cb0[i0]+cb1[i1]+cb2[i2] (same add order as res accumulation) -> s_A bf16
    #pragma unroll
    for (int ct = 0; ct < 8; ++ct)
        #pragma unroll
        for (int e = 0; e < 4; ++e) {
            const int co = ct * 16 + nn;
            const float r = cb0[(long)bis0[e] * D_H + co]
                          + cb1[(long)bis1[e] * D_H + co]
                          + cb2[(long)bis2[e] * D_H + co];
            s_A[(wrow + qd * 4 + e) * SA + co] = f2bf(r);
        }

    // ---- Phase 3: recon = restored @ Wdec^T; 2 x 64KB chunks, diff vs fp32 emb ----
    float local_rec = 0.f;
    {
        bf16x8 af[4];
        #pragma unroll
        for (int ks = 0; ks < 4; ++ks)
            af[ks] = *(const bf16x8*)&s_A[(wrow + nn) * SA + ks * 32 + qd * 8];
        #pragma unroll 1
        for (int r3 = 0; r3 < 2; ++r3) {
            __syncthreads();
            COPY64(wsb + 163840 + r3 * 32768);
            __syncthreads();
            #pragma unroll 2
            for (int ctc = 0; ctc < 16; ++ctc) {
                f32x4 rr = {0.f,0.f,0.f,0.f};
                #pragma unroll
                for (int ks = 0; ks < 4; ++ks) {
                    bf16x8 bf = *(const bf16x8*)&s_B[(ctc * 4 + ks) * 512 + lane * 8];
                    rr = __builtin_amdgcn_mfma_f32_16x16x32_bf16(af[ks], bf, rr, 0, 0, 0);
                }
                const int col = r3 * 256 + ctc * 16 + nn;
                #pragma unroll
                for (int e = 0; e < 4; ++e) {
                    const float e0 = emb[(blkRow + wrow + qd * 4 + e) * D_IN + col];
                    const float d = rr[e] - e0;
                    local_rec += d * d;
                }
            }
        }
    }
#undef COPY64

    // ---- wave shuffle reduce, one atomic pair per wave ----
    float r1 = local_rq, r2 = local_rec;
    #pragma unroll
    for (int m = 32; m >= 1; m >>= 1) { r1 += __shfl_xor(r1, m); r2 += __shfl_xor(r2, m); }
    if (lane == 0) { atomicAdd(acc_rq, r1); atomicAdd(acc_recon, r2); }
}

__global__ void rqvae_finalize(const float* __restrict__ acc,
                               const int* __restrict__ used,
                               float* __restrict__ out)
{
    __shared__ int s_sum[4];
    const int tid = threadIdx.x;
    for (int t = 0; t < 3; ++t) {
        int v = (used[t * K_CODES + tid] != 0) ? 1 : 0;
        #pragma unroll
        for (int off = 32; off >= 1; off >>= 1) v += __shfl_down(v, off);
        if ((tid & 63) == 0) s_sum[tid >> 6] = v;
        __syncthreads();
        if (tid == 0) out[3 + t] = (float)(s_sum[0] + s_sum[1] + s_sum[2] + s_sum[3]);
        __syncthreads();
    }
    if (tid == 0) {
        const float rq    = 1.25f * acc[0] / ((float)N_ROWS * 128.0f);
        const float recon =         acc[1] / ((float)N_ROWS * 512.0f);
        out[0] = recon + rq;
        out[1] = recon;
        out[2] = rq;
    }
}

extern "C" void kernel_launch(void* const* d_in, const int* in_sizes, int n_in,
                              void* d_out, int out_size, void* d_ws, size_t ws_size,
                              hipStream_t stream) {
    const float* emb  = (const float*)d_in[0];
    const float* Wenc = (const float*)d_in[1];
    const float* Wdec = (const float*)d_in[2];
    const float* cb0  = (const float*)d_in[3];
    const float* cb1  = (const float*)d_in[4];
    const float* cb2  = (const float*)d_in[5];

    // workspace layout (bytes): [0] 2 f32 acc | [64] 768 int used | [3200] 768 f32 norms | [8192] 448KB bf16 frags
    float* ws_f  = (float*)d_ws;
    int*   used  = (int*)((char*)d_ws + 64);
    float* norms = (float*)((char*)d_ws + 3200);
    unsigned short* wsb = (unsigned short*)((char*)d_ws + 8192);

    hipMemsetAsync(d_ws, 0, 3200, stream);
    rqvae_prep<<<115, PNT, 0, stream>>>(Wenc, Wdec, cb0, cb1, cb2, wsb, norms);
    rqvae_main<<<NBLK, NT, 0, stream>>>(emb, cb0, cb1, cb2, wsb, norms,
                                        ws_f + 0, ws_f + 1, used);
    rqvae_finalize<<<1, PNT, 0, stream>>>(ws_f, used, (float*)d_out);
}

// Round 11
// 547.765 us; speedup vs baseline: 1.1597x; 1.1597x over previous
//
#include <hip/hip_runtime.h>

#define N_ROWS   131072
#define D_IN     512
#define D_H      128
#define K_CODES  256
#define NT       256          // 4 waves
#define RPB      128          // rows per block: 32 per wave (2 x 16-row MFMA tiles)
#define NBLK     (N_ROWS / RPB)
#define SA       136          // s_A row stride in bf16 elems (272 B, breaks power-of-2)

typedef __attribute__((ext_vector_type(8))) short bf16x8;
typedef __attribute__((ext_vector_type(4))) float f32x4;

__device__ inline unsigned short f2bf(float f) {
    unsigned u = __float_as_uint(f);
    return (unsigned short)((u + 0x7FFFu + ((u >> 16) & 1u)) >> 16);
}
__device__ inline ushort4 f2bf4(float4 v) {
    return make_ushort4(f2bf(v.x), f2bf(v.y), f2bf(v.z), f2bf(v.w));
}

// ---------------- prep: reorder weights/codebooks into MFMA B-fragment order ----------------
// B-fragment order: frag(ct,ks) is 64 lanes x 8 bf16, lane = qd*16+nn holds
// B[n = ct*16+nn][k = ks*32 + qd*8 + j], j=0..7.  One 32KB "round" = 8 ct x 4 ks.
// wsb layout (ushorts): [0..65535] Wenc rounds kc=0..3 | [65536..163839] cb (t,half) rounds | [163840..229375] Wdec rounds c=0..3
__global__ void rqvae_prep(const float* __restrict__ Wenc,
                           const float* __restrict__ Wdec,
                           const float* __restrict__ cb0,
                           const float* __restrict__ cb1,
                           const float* __restrict__ cb2,
                           unsigned short* __restrict__ wsb,
                           float* __restrict__ norms)
{
    const int tid = threadIdx.x;
    const int b = blockIdx.x;
    const float* cbs[3] = {cb0, cb1, cb2};
    if (b < 112) {
        const int g = b * 256 + tid;            // ushort8 group id, 0..28671
        const int lane = g & 63, ks = (g >> 6) & 3, ct = (g >> 8) & 7;
        const int nn = lane & 15, qd = lane >> 4;
        const float* src;
        if (g < 8192) {                         // Wenc: kc = g>>11
            const int kc = g >> 11;
            src = Wenc + (ct * 16 + nn) * D_IN + kc * 128 + ks * 32 + qd * 8;
        } else if (g < 20480) {                 // cb: t = (g-8192)>>12, half = bit 11
            const int r = g - 8192;
            const int t = r >> 12, half = (r >> 11) & 1;
            src = cbs[t] + (long)(half * 128 + ct * 16 + nn) * D_H + ks * 32 + qd * 8;
        } else {                                // Wdec: c = (g-20480)>>11
            const int r = g - 20480;
            const int c = r >> 11;
            src = Wdec + (long)(c * 128 + ct * 16 + nn) * D_H + ks * 32 + qd * 8;
        }
        float4 v0 = *(const float4*)(src);
        float4 v1 = *(const float4*)(src + 4);
        *(ushort4*)(wsb + (long)g * 8)     = f2bf4(v0);
        *(ushort4*)(wsb + (long)g * 8 + 4) = f2bf4(v1);
    } else {
        const int t = b - 112;                  // norm blocks: one code per thread
        const float4* r = (const float4*)(cbs[t] + (long)tid * D_H);
        float s = 0.f;
        #pragma unroll
        for (int d = 0; d < 32; ++d) { float4 v = r[d]; s += v.x*v.x + v.y*v.y + v.z*v.z + v.w*v.w; }
        norms[t * K_CODES + tid] = -0.5f * s;
    }
}

// ---------------- main ----------------
// Round-7 champion (283us main) + register-pressure fix for LOAD BATCHING:
// the champion's rem[2][8]+res[2][8] = 128 acc regs + 116 VGPR ~= 244/256 budget
// left ~10 free VGPRs -> the 16 A-stage loads issued in dribbles of 2-3, paying
// ~900cy HBM latency ~6x per round (the >100us of no-issue stall in the pipe sum).
// Edits: (1) res eliminated -- 3x2x4 winning indices kept, restored re-gathered
// (c0+c1)+c2 at phase-3 entry (bit-exact, proven rounds 5/6/10); (2) A-stage
// loads explicitly batched 8-deep into temps; (3) B-copy batched 8-deep.
// Everything else (sync structure, tiling, rounds, rot) byte-identical.
__global__ __launch_bounds__(NT, 2) void rqvae_main(
    const float* __restrict__ emb,
    const float* __restrict__ cb0,
    const float* __restrict__ cb1,
    const float* __restrict__ cb2,
    const unsigned short* __restrict__ wsb,
    const float* __restrict__ norms,
    float* __restrict__ acc_rq,
    float* __restrict__ acc_recon,
    int* __restrict__ used)
{
    __shared__ unsigned short s_A[RPB * SA];   // 34816 B: A operand (emb chunk / rem / restored), padded
    __shared__ unsigned short s_B[16384];      // 32768 B: one B round, fragment-linear
    __shared__ float s_cn[3 * K_CODES];        // 3072 B

    const int tid  = threadIdx.x;
    const int wv   = tid >> 6;
    const int lane = tid & 63;
    const int nn   = lane & 15;
    const int qd   = lane >> 4;
    const long blkRow = (long)blockIdx.x * RPB;
    const int rot  = (blockIdx.x >> 3) & 3;    // same-XCD decorrelator (neutral, kept)
    const float* cbs[3] = {cb0, cb1, cb2};

    for (int i = tid; i < 3 * K_CODES; i += NT) s_cn[i] = norms[i];

    // B: 32KB round copy, batched 8 loads -> 8 stores (temps give the loads ILP)
#define COPYB(roundbase) do {                                                   \
        const bf16x8* _s = (const bf16x8*)(roundbase);                          \
        bf16x8* _d = (bf16x8*)s_B;                                              \
        bf16x8 _t[8];                                                           \
        _Pragma("unroll")                                                       \
        for (int _i = 0; _i < 8; ++_i) _t[_i] = _s[tid + _i * NT];              \
        _Pragma("unroll")                                                       \
        for (int _i = 0; _i < 8; ++_i) _d[tid + _i * NT] = _t[_i];              \
    } while (0)

    f32x4 rem[2][8];
    #pragma unroll
    for (int rt = 0; rt < 2; ++rt)
        #pragma unroll
        for (int ct = 0; ct < 8; ++ct) rem[rt][ct] = {0.f,0.f,0.f,0.f};

    // ---- Phase 1: latent = emb @ Wenc^T (4 rounds of K=128, rotated order) ----
    for (int kk = 0; kk < 4; ++kk) {
        const int kc = (kk + rot) & 3;
        __syncthreads();
        // A: 128 rows x 32 float4, two batches of 8 loads each (8KB/wave in flight)
        #pragma unroll
        for (int hb = 0; hb < 2; ++hb) {
            float4 ta[8];
            #pragma unroll
            for (int i = 0; i < 8; ++i) {
                const int g = tid + (hb * 8 + i) * NT, row = g >> 5, c4 = g & 31;
                ta[i] = *(const float4*)(emb + (blkRow + row) * D_IN + kc * 128 + c4 * 4);
            }
            #pragma unroll
            for (int i = 0; i < 8; ++i) {
                const int g = tid + (hb * 8 + i) * NT, row = g >> 5, c4 = g & 31;
                *(ushort4*)&s_A[row * SA + c4 * 4] = f2bf4(ta[i]);
            }
        }
        COPYB(wsb + kc * 16384);
        __syncthreads();
        bf16x8 af[2][4];
        #pragma unroll
        for (int rt = 0; rt < 2; ++rt)
            #pragma unroll
            for (int ks = 0; ks < 4; ++ks)
                af[rt][ks] = *(const bf16x8*)&s_A[(wv * 32 + rt * 16 + nn) * SA + ks * 32 + qd * 8];
        #pragma unroll
        for (int ct = 0; ct < 8; ++ct)
            #pragma unroll
            for (int ks = 0; ks < 4; ++ks) {
                bf16x8 bf = *(const bf16x8*)&s_B[(ct * 4 + ks) * 512 + lane * 8];
                rem[0][ct] = __builtin_amdgcn_mfma_f32_16x16x32_bf16(af[0][ks], bf, rem[0][ct], 0, 0, 0);
                rem[1][ct] = __builtin_amdgcn_mfma_f32_16x16x32_bf16(af[1][ks], bf, rem[1][ct], 0, 0, 0);
            }
    }

    // latent -> s_A bf16 (wave-private rows)
    #pragma unroll
    for (int rt = 0; rt < 2; ++rt)
        #pragma unroll
        for (int ct = 0; ct < 8; ++ct)
            #pragma unroll
            for (int e = 0; e < 4; ++e)
                s_A[(wv * 32 + rt * 16 + qd * 4 + e) * SA + ct * 16 + nn] = f2bf(rem[rt][ct][e]);

    // ---- Phase 2: three RQ stages (halves rotated within each stage) ----
    float local_rq = 0.f;
    int bis0[2][4], bis1[2][4], bis2[2][4];    // winning codes per stage (res re-gathered later)
    for (int t = 0; t < 3; ++t) {
        const float* __restrict__ cb = cbs[t];
        float bv[2][4]; int bi[2][4];
        #pragma unroll
        for (int rt = 0; rt < 2; ++rt)
            #pragma unroll
            for (int e = 0; e < 4; ++e) { bv[rt][e] = -3.402823466e38f; bi[rt][e] = 0; }

        bf16x8 af[2][4];
        #pragma unroll
        for (int rt = 0; rt < 2; ++rt)
            #pragma unroll
            for (int ks = 0; ks < 4; ++ks)
                af[rt][ks] = *(const bf16x8*)&s_A[(wv * 32 + rt * 16 + nn) * SA + ks * 32 + qd * 8];

        for (int hh = 0; hh < 2; ++hh) {
            const int half = hh ^ (rot & 1);
            __syncthreads();
            COPYB(wsb + 65536 + (t * 2 + half) * 16384);
            __syncthreads();
            #pragma unroll
            for (int ct = 0; ct < 8; ++ct) {
                f32x4 s0 = {0.f,0.f,0.f,0.f}, s1 = {0.f,0.f,0.f,0.f};
                #pragma unroll
                for (int ks = 0; ks < 4; ++ks) {
                    bf16x8 bf = *(const bf16x8*)&s_B[(ct * 4 + ks) * 512 + lane * 8];
                    s0 = __builtin_amdgcn_mfma_f32_16x16x32_bf16(af[0][ks], bf, s0, 0, 0, 0);
                    s1 = __builtin_amdgcn_mfma_f32_16x16x32_bf16(af[1][ks], bf, s1, 0, 0, 0);
                }
                const int code = half * 128 + ct * 16 + nn;
                const float cn = s_cn[t * K_CODES + code];
                #pragma unroll
                for (int e = 0; e < 4; ++e) {
                    const float v0 = s0[e] + cn;
                    if (v0 > bv[0][e] || (v0 == bv[0][e] && code < bi[0][e])) { bv[0][e] = v0; bi[0][e] = code; }
                    const float v1 = s1[e] + cn;
                    if (v1 > bv[1][e] || (v1 == bv[1][e] && code < bi[1][e])) { bv[1][e] = v1; bi[1][e] = code; }
                }
            }
        }
        // argmax over the 16 nn-lanes of each quad (tie -> lowest index)
        #pragma unroll
        for (int rt = 0; rt < 2; ++rt)
            #pragma unroll
            for (int e = 0; e < 4; ++e) {
                float v = bv[rt][e]; int i0 = bi[rt][e];
                #pragma unroll
                for (int m = 8; m >= 1; m >>= 1) {
                    const float ov = __shfl_xor(v, m);
                    const int   oi = __shfl_xor(i0, m);
                    if (ov > v || (ov == v && oi < i0)) { v = ov; i0 = oi; }
                }
                bi[rt][e] = i0;
                if (t == 0) bis0[rt][e] = i0; else if (t == 1) bis1[rt][e] = i0; else bis2[rt][e] = i0;
                if (nn == 0) used[t * K_CODES + i0] = 1;
            }
        // update rem with fp32 codebook rows (res NOT kept)
        #pragma unroll
        for (int rt = 0; rt < 2; ++rt)
            #pragma unroll
            for (int ct = 0; ct < 8; ++ct)
                #pragma unroll
                for (int e = 0; e < 4; ++e) {
                    const float c = cb[(long)bi[rt][e] * D_H + ct * 16 + nn];
                    const float r = rem[rt][ct][e] - c;
                    rem[rt][ct][e] = r;
                    local_rq += r * r;
                    if (t < 2)
                        s_A[(wv * 32 + rt * 16 + qd * 4 + e) * SA + ct * 16 + nn] = f2bf(r);
                }
    }

    // restored = cb0[i0]+cb1[i1]+cb2[i2] re-gathered (same add order as res += c) -> s_A bf16
    #pragma unroll
    for (int rt = 0; rt < 2; ++rt)
        #pragma unroll
        for (int ct = 0; ct < 8; ++ct)
            #pragma unroll
            for (int e = 0; e < 4; ++e) {
                const int co = ct * 16 + nn;
                const float r = cb0[(long)bis0[rt][e] * D_H + co]
                              + cb1[(long)bis1[rt][e] * D_H + co]
                              + cb2[(long)bis2[rt][e] * D_H + co];
                s_A[(wv * 32 + rt * 16 + qd * 4 + e) * SA + co] = f2bf(r);
            }

    // ---- Phase 3: recon = restored @ Wdec^T (rotated col-chunk order), diff vs fp32 emb ----
    float local_rec = 0.f;
    {
        bf16x8 af[2][4];
        #pragma unroll
        for (int rt = 0; rt < 2; ++rt)
            #pragma unroll
            for (int ks = 0; ks < 4; ++ks)
                af[rt][ks] = *(const bf16x8*)&s_A[(wv * 32 + rt * 16 + nn) * SA + ks * 32 + qd * 8];
        for (int cc = 0; cc < 4; ++cc) {
            const int c = (cc + rot) & 3;
            __syncthreads();
            COPYB(wsb + 163840 + c * 16384);
            __syncthreads();
            #pragma unroll
            for (int ct = 0; ct < 8; ++ct) {
                f32x4 r0 = {0.f,0.f,0.f,0.f}, r1 = {0.f,0.f,0.f,0.f};
                #pragma unroll
                for (int ks = 0; ks < 4; ++ks) {
                    bf16x8 bf = *(const bf16x8*)&s_B[(ct * 4 + ks) * 512 + lane * 8];
                    r0 = __builtin_amdgcn_mfma_f32_16x16x32_bf16(af[0][ks], bf, r0, 0, 0, 0);
                    r1 = __builtin_amdgcn_mfma_f32_16x16x32_bf16(af[1][ks], bf, r1, 0, 0, 0);
                }
                const int col = c * 128 + ct * 16 + nn;
                #pragma unroll
                for (int e = 0; e < 4; ++e) {
                    const float e0 = emb[(blkRow + wv * 32 +      qd * 4 + e) * D_IN + col];
                    const float e1 = emb[(blkRow + wv * 32 + 16 + qd * 4 + e) * D_IN + col];
                    const float d0 = r0[e] - e0;
                    const float d1 = r1[e] - e1;
                    local_rec += d0 * d0 + d1 * d1;
                }
            }
        }
    }
#undef COPYB

    // ---- wave shuffle reduce, one atomic pair per wave ----
    float r1 = local_rq, r2 = local_rec;
    #pragma unroll
    for (int m = 32; m >= 1; m >>= 1) { r1 += __shfl_xor(r1, m); r2 += __shfl_xor(r2, m); }
    if (lane == 0) { atomicAdd(acc_rq, r1); atomicAdd(acc_recon, r2); }
}

__global__ void rqvae_finalize(const float* __restrict__ acc,
                               const int* __restrict__ used,
                               float* __restrict__ out)
{
    __shared__ int s_sum[4];
    const int tid = threadIdx.x;
    for (int t = 0; t < 3; ++t) {
        int v = (used[t * K_CODES + tid] != 0) ? 1 : 0;
        #pragma unroll
        for (int off = 32; off >= 1; off >>= 1) v += __shfl_down(v, off);
        if ((tid & 63) == 0) s_sum[tid >> 6] = v;
        __syncthreads();
        if (tid == 0) out[3 + t] = (float)(s_sum[0] + s_sum[1] + s_sum[2] + s_sum[3]);
        __syncthreads();
    }
    if (tid == 0) {
        const float rq    = 1.25f * acc[0] / ((float)N_ROWS * 128.0f);
        const float recon =         acc[1] / ((float)N_ROWS * 512.0f);
        out[0] = recon + rq;
        out[1] = recon;
        out[2] = rq;
    }
}

extern "C" void kernel_launch(void* const* d_in, const int* in_sizes, int n_in,
                              void* d_out, int out_size, void* d_ws, size_t ws_size,
                              hipStream_t stream) {
    const float* emb  = (const float*)d_in[0];
    const float* Wenc = (const float*)d_in[1];
    const float* Wdec = (const float*)d_in[2];
    const float* cb0  = (const float*)d_in[3];
    const float* cb1  = (const float*)d_in[4];
    const float* cb2  = (const float*)d_in[5];

    // workspace layout (bytes): [0] 2 f32 acc | [64] 768 int used | [3200] 768 f32 norms | [8192] 448KB bf16 frags
    float* ws_f  = (float*)d_ws;
    int*   used  = (int*)((char*)d_ws + 64);
    float* norms = (float*)((char*)d_ws + 3200);
    unsigned short* wsb = (unsigned short*)((char*)d_ws + 8192);

    hipMemsetAsync(d_ws, 0, 3200, stream);
    rqvae_prep<<<115, NT, 0, stream>>>(Wenc, Wdec, cb0, cb1, cb2, wsb, norms);
    rqvae_main<<<NBLK, NT, 0, stream>>>(emb, cb0, cb1, cb2, wsb, norms,
                                        ws_f + 0, ws_f + 1, used);
    rqvae_finalize<<<1, NT, 0, stream>>>(ws_f, used, (float*)d_out);
}

// Round 12
// 544.405 us; speedup vs baseline: 1.1669x; 1.0062x over previous
//
#include <hip/hip_runtime.h>

#define N_ROWS   131072
#define D_IN     512
#define D_H      128
#define K_CODES  256
#define NT       256          // 4 waves
#define RPB      128          // rows per block: 32 per wave (2 x 16-row MFMA tiles)
#define NBLK     (N_ROWS / RPB)
#define SA       136          // s_A row stride in bf16 elems (272 B, breaks power-of-2)

typedef __attribute__((ext_vector_type(8))) short bf16x8;
typedef __attribute__((ext_vector_type(4))) float f32x4;

__device__ inline unsigned short f2bf(float f) {
    unsigned u = __float_as_uint(f);
    return (unsigned short)((u + 0x7FFFu + ((u >> 16) & 1u)) >> 16);
}
__device__ inline ushort4 f2bf4(float4 v) {
    return make_ushort4(f2bf(v.x), f2bf(v.y), f2bf(v.z), f2bf(v.w));
}
// packed RNE f32->bf16 pair (bit-identical to f2bf): one VALU op per 2 elems
__device__ __forceinline__ unsigned cvtpk(float lo, float hi) {
    unsigned r;
    asm("v_cvt_pk_bf16_f32 %0, %1, %2" : "=v"(r) : "v"(lo), "v"(hi));
    return r;
}

// ---------------- prep: reorder weights/codebooks into MFMA B-fragment order ----------------
// B-fragment order: frag(ct,ks) is 64 lanes x 8 bf16, lane = qd*16+nn holds
// B[n = ct*16+nn][k = ks*32 + qd*8 + j], j=0..7.  One 32KB "round" = 8 ct x 4 ks.
// wsb layout (ushorts): [0..65535] Wenc rounds kc=0..3 | [65536..163839] cb (t,half) rounds | [163840..229375] Wdec rounds c=0..3
// Block 112 additionally zeros the 3200-byte acc/used area (replaces hipMemsetAsync).
__global__ void rqvae_prep(const float* __restrict__ Wenc,
                           const float* __restrict__ Wdec,
                           const float* __restrict__ cb0,
                           const float* __restrict__ cb1,
                           const float* __restrict__ cb2,
                           unsigned short* __restrict__ wsb,
                           float* __restrict__ norms,
                           float* __restrict__ ws_zero)
{
    const int tid = threadIdx.x;
    const int b = blockIdx.x;
    const float* cbs[3] = {cb0, cb1, cb2};
    if (b < 112) {
        const int g = b * 256 + tid;            // ushort8 group id, 0..28671
        const int lane = g & 63, ks = (g >> 6) & 3, ct = (g >> 8) & 7;
        const int nn = lane & 15, qd = lane >> 4;
        const float* src;
        if (g < 8192) {                         // Wenc: kc = g>>11
            const int kc = g >> 11;
            src = Wenc + (ct * 16 + nn) * D_IN + kc * 128 + ks * 32 + qd * 8;
        } else if (g < 20480) {                 // cb: t = (g-8192)>>12, half = bit 11
            const int r = g - 8192;
            const int t = r >> 12, half = (r >> 11) & 1;
            src = cbs[t] + (long)(half * 128 + ct * 16 + nn) * D_H + ks * 32 + qd * 8;
        } else {                                // Wdec: c = (g-20480)>>11
            const int r = g - 20480;
            const int c = r >> 11;
            src = Wdec + (long)(c * 128 + ct * 16 + nn) * D_H + ks * 32 + qd * 8;
        }
        float4 v0 = *(const float4*)(src);
        float4 v1 = *(const float4*)(src + 4);
        *(ushort4*)(wsb + (long)g * 8)     = f2bf4(v0);
        *(ushort4*)(wsb + (long)g * 8 + 4) = f2bf4(v1);
    } else {
        const int t = b - 112;                  // norm blocks: one code per thread
        if (t == 0)                             // zero acc (2 f32) + used (768 int): 800 words
            for (int i = tid; i < 800; i += 256) ws_zero[i] = 0.f;
        const float4* r = (const float4*)(cbs[t] + (long)tid * D_H);
        float s = 0.f;
        #pragma unroll
        for (int d = 0; d < 32; ++d) { float4 v = r[d]; s += v.x*v.x + v.y*v.y + v.z*v.z + v.w*v.w; }
        norms[t * K_CODES + tid] = -0.5f * s;
    }
}

// ---------------- main ----------------
// Round-7/11 champion structure (283us main; robust against 9 falsified
// structural theories spanning 280-460us). This round: pipe-WORK cuts only.
//  (1) A-staging f32->bf16 via v_cvt_pk_bf16_f32 (isolated this time -- round 9
//      bundled it with the DMA B-copy which regressed; VALUBusy 18->15.7 showed
//      the cvt_pk itself removed real VALU work). B-copy stays VALU (batched).
//  (2) res accumulator eliminated (indices kept, restored re-gathered
//      (c0+c1)+c2 -- bit-exact, proven rounds 5/6/10/11).
// Harness context: workspace re-poison fill = ~160us/iter (measured round 8),
// a fixed floor outside kernel control.
__global__ __launch_bounds__(NT, 2) void rqvae_main(
    const float* __restrict__ emb,
    const float* __restrict__ cb0,
    const float* __restrict__ cb1,
    const float* __restrict__ cb2,
    const unsigned short* __restrict__ wsb,
    const float* __restrict__ norms,
    float* __restrict__ acc_rq,
    float* __restrict__ acc_recon,
    int* __restrict__ used)
{
    __shared__ unsigned short s_A[RPB * SA];   // 34816 B: A operand (emb chunk / rem / restored), padded
    __shared__ unsigned short s_B[16384];      // 32768 B: one B round, fragment-linear
    __shared__ float s_cn[3 * K_CODES];        // 3072 B

    const int tid  = threadIdx.x;
    const int wv   = tid >> 6;
    const int lane = tid & 63;
    const int nn   = lane & 15;
    const int qd   = lane >> 4;
    const long blkRow = (long)blockIdx.x * RPB;
    const int rot  = (blockIdx.x >> 3) & 3;    // same-XCD decorrelator (neutral, kept)
    const float* cbs[3] = {cb0, cb1, cb2};

    for (int i = tid; i < 3 * K_CODES; i += NT) s_cn[i] = norms[i];

    // B: 32KB round copy, batched 8 loads -> 8 stores
#define COPYB(roundbase) do {                                                   \
        const bf16x8* _s = (const bf16x8*)(roundbase);                          \
        bf16x8* _d = (bf16x8*)s_B;                                              \
        bf16x8 _t[8];                                                           \
        _Pragma("unroll")                                                       \
        for (int _i = 0; _i < 8; ++_i) _t[_i] = _s[tid + _i * NT];              \
        _Pragma("unroll")                                                       \
        for (int _i = 0; _i < 8; ++_i) _d[tid + _i * NT] = _t[_i];              \
    } while (0)

    f32x4 rem[2][8];
    #pragma unroll
    for (int rt = 0; rt < 2; ++rt)
        #pragma unroll
        for (int ct = 0; ct < 8; ++ct) rem[rt][ct] = {0.f,0.f,0.f,0.f};

    // ---- Phase 1: latent = emb @ Wenc^T (4 rounds of K=128, rotated order) ----
    for (int kk = 0; kk < 4; ++kk) {
        const int kc = (kk + rot) & 3;
        __syncthreads();
        // A: 128 rows x 32 float4, two batches of 8 loads; cvt via packed bf16
        #pragma unroll
        for (int hb = 0; hb < 2; ++hb) {
            float4 ta[8];
            #pragma unroll
            for (int i = 0; i < 8; ++i) {
                const int g = tid + (hb * 8 + i) * NT, row = g >> 5, c4 = g & 31;
                ta[i] = *(const float4*)(emb + (blkRow + row) * D_IN + kc * 128 + c4 * 4);
            }
            #pragma unroll
            for (int i = 0; i < 8; ++i) {
                const int g = tid + (hb * 8 + i) * NT, row = g >> 5, c4 = g & 31;
                uint2 p; p.x = cvtpk(ta[i].x, ta[i].y); p.y = cvtpk(ta[i].z, ta[i].w);
                *(uint2*)&s_A[row * SA + c4 * 4] = p;
            }
        }
        COPYB(wsb + kc * 16384);
        __syncthreads();
        bf16x8 af[2][4];
        #pragma unroll
        for (int rt = 0; rt < 2; ++rt)
            #pragma unroll
            for (int ks = 0; ks < 4; ++ks)
                af[rt][ks] = *(const bf16x8*)&s_A[(wv * 32 + rt * 16 + nn) * SA + ks * 32 + qd * 8];
        #pragma unroll
        for (int ct = 0; ct < 8; ++ct)
            #pragma unroll
            for (int ks = 0; ks < 4; ++ks) {
                bf16x8 bf = *(const bf16x8*)&s_B[(ct * 4 + ks) * 512 + lane * 8];
                rem[0][ct] = __builtin_amdgcn_mfma_f32_16x16x32_bf16(af[0][ks], bf, rem[0][ct], 0, 0, 0);
                rem[1][ct] = __builtin_amdgcn_mfma_f32_16x16x32_bf16(af[1][ks], bf, rem[1][ct], 0, 0, 0);
            }
    }

    // latent -> s_A bf16 (wave-private rows)
    #pragma unroll
    for (int rt = 0; rt < 2; ++rt)
        #pragma unroll
        for (int ct = 0; ct < 8; ++ct)
            #pragma unroll
            for (int e = 0; e < 4; ++e)
                s_A[(wv * 32 + rt * 16 + qd * 4 + e) * SA + ct * 16 + nn] = f2bf(rem[rt][ct][e]);

    // ---- Phase 2: three RQ stages (halves rotated within each stage) ----
    float local_rq = 0.f;
    int bis0[2][4], bis1[2][4], bis2[2][4];    // winning codes per stage (res re-gathered later)
    for (int t = 0; t < 3; ++t) {
        const float* __restrict__ cb = cbs[t];
        float bv[2][4]; int bi[2][4];
        #pragma unroll
        for (int rt = 0; rt < 2; ++rt)
            #pragma unroll
            for (int e = 0; e < 4; ++e) { bv[rt][e] = -3.402823466e38f; bi[rt][e] = 0; }

        bf16x8 af[2][4];
        #pragma unroll
        for (int rt = 0; rt < 2; ++rt)
            #pragma unroll
            for (int ks = 0; ks < 4; ++ks)
                af[rt][ks] = *(const bf16x8*)&s_A[(wv * 32 + rt * 16 + nn) * SA + ks * 32 + qd * 8];

        for (int hh = 0; hh < 2; ++hh) {
            const int half = hh ^ (rot & 1);
            __syncthreads();
            COPYB(wsb + 65536 + (t * 2 + half) * 16384);
            __syncthreads();
            #pragma unroll
            for (int ct = 0; ct < 8; ++ct) {
                f32x4 s0 = {0.f,0.f,0.f,0.f}, s1 = {0.f,0.f,0.f,0.f};
                #pragma unroll
                for (int ks = 0; ks < 4; ++ks) {
                    bf16x8 bf = *(const bf16x8*)&s_B[(ct * 4 + ks) * 512 + lane * 8];
                    s0 = __builtin_amdgcn_mfma_f32_16x16x32_bf16(af[0][ks], bf, s0, 0, 0, 0);
                    s1 = __builtin_amdgcn_mfma_f32_16x16x32_bf16(af[1][ks], bf, s1, 0, 0, 0);
                }
                const int code = half * 128 + ct * 16 + nn;
                const float cn = s_cn[t * K_CODES + code];
                #pragma unroll
                for (int e = 0; e < 4; ++e) {
                    const float v0 = s0[e] + cn;
                    if (v0 > bv[0][e] || (v0 == bv[0][e] && code < bi[0][e])) { bv[0][e] = v0; bi[0][e] = code; }
                    const float v1 = s1[e] + cn;
                    if (v1 > bv[1][e] || (v1 == bv[1][e] && code < bi[1][e])) { bv[1][e] = v1; bi[1][e] = code; }
                }
            }
        }
        // argmax over the 16 nn-lanes of each quad (tie -> lowest index)
        #pragma unroll
        for (int rt = 0; rt < 2; ++rt)
            #pragma unroll
            for (int e = 0; e < 4; ++e) {
                float v = bv[rt][e]; int i0 = bi[rt][e];
                #pragma unroll
                for (int m = 8; m >= 1; m >>= 1) {
                    const float ov = __shfl_xor(v, m);
                    const int   oi = __shfl_xor(i0, m);
                    if (ov > v || (ov == v && oi < i0)) { v = ov; i0 = oi; }
                }
                bi[rt][e] = i0;
                if (t == 0) bis0[rt][e] = i0; else if (t == 1) bis1[rt][e] = i0; else bis2[rt][e] = i0;
                if (nn == 0) used[t * K_CODES + i0] = 1;
            }
        // update rem with fp32 codebook rows (res NOT kept)
        #pragma unroll
        for (int rt = 0; rt < 2; ++rt)
            #pragma unroll
            for (int ct = 0; ct < 8; ++ct)
                #pragma unroll
                for (int e = 0; e < 4; ++e) {
                    const float c = cb[(long)bi[rt][e] * D_H + ct * 16 + nn];
                    const float r = rem[rt][ct][e] - c;
                    rem[rt][ct][e] = r;
                    local_rq += r * r;
                    if (t < 2)
                        s_A[(wv * 32 + rt * 16 + qd * 4 + e) * SA + ct * 16 + nn] = f2bf(r);
                }
    }

    // restored = cb0[i0]+cb1[i1]+cb2[i2] re-gathered (same add order as res += c) -> s_A bf16
    #pragma unroll
    for (int rt = 0; rt < 2; ++rt)
        #pragma unroll
        for (int ct = 0; ct < 8; ++ct)
            #pragma unroll
            for (int e = 0; e < 4; ++e) {
                const int co = ct * 16 + nn;
                const float r = cb0[(long)bis0[rt][e] * D_H + co]
                              + cb1[(long)bis1[rt][e] * D_H + co]
                              + cb2[(long)bis2[rt][e] * D_H + co];
                s_A[(wv * 32 + rt * 16 + qd * 4 + e) * SA + co] = f2bf(r);
            }

    // ---- Phase 3: recon = restored @ Wdec^T (rotated col-chunk order), diff vs fp32 emb ----
    float local_rec = 0.f;
    {
        bf16x8 af[2][4];
        #pragma unroll
        for (int rt = 0; rt < 2; ++rt)
            #pragma unroll
            for (int ks = 0; ks < 4; ++ks)
                af[rt][ks] = *(const bf16x8*)&s_A[(wv * 32 + rt * 16 + nn) * SA + ks * 32 + qd * 8];
        for (int cc = 0; cc < 4; ++cc) {
            const int c = (cc + rot) & 3;
            __syncthreads();
            COPYB(wsb + 163840 + c * 16384);
            __syncthreads();
            #pragma unroll
            for (int ct = 0; ct < 8; ++ct) {
                f32x4 r0 = {0.f,0.f,0.f,0.f}, r1 = {0.f,0.f,0.f,0.f};
                #pragma unroll
                for (int ks = 0; ks < 4; ++ks) {
                    bf16x8 bf = *(const bf16x8*)&s_B[(ct * 4 + ks) * 512 + lane * 8];
                    r0 = __builtin_amdgcn_mfma_f32_16x16x32_bf16(af[0][ks], bf, r0, 0, 0, 0);
                    r1 = __builtin_amdgcn_mfma_f32_16x16x32_bf16(af[1][ks], bf, r1, 0, 0, 0);
                }
                const int col = c * 128 + ct * 16 + nn;
                #pragma unroll
                for (int e = 0; e < 4; ++e) {
                    const float e0 = emb[(blkRow + wv * 32 +      qd * 4 + e) * D_IN + col];
                    const float e1 = emb[(blkRow + wv * 32 + 16 + qd * 4 + e) * D_IN + col];
                    const float d0 = r0[e] - e0;
                    const float d1 = r1[e] - e1;
                    local_rec += d0 * d0 + d1 * d1;
                }
            }
        }
    }
#undef COPYB

    // ---- wave shuffle reduce, one atomic pair per wave ----
    float r1 = local_rq, r2 = local_rec;
    #pragma unroll
    for (int m = 32; m >= 1; m >>= 1) { r1 += __shfl_xor(r1, m); r2 += __shfl_xor(r2, m); }
    if (lane == 0) { atomicAdd(acc_rq, r1); atomicAdd(acc_recon, r2); }
}

// one-pass finalize: 3 concurrent used-reductions, single barrier
__global__ void rqvae_finalize(const float* __restrict__ acc,
                               const int* __restrict__ used,
                               float* __restrict__ out)
{
    __shared__ int s_sum[4][3];
    const int tid = threadIdx.x;
    int v0 = (used[tid] != 0) ? 1 : 0;
    int v1 = (used[K_CODES + tid] != 0) ? 1 : 0;
    int v2 = (used[2 * K_CODES + tid] != 0) ? 1 : 0;
    #pragma unroll
    for (int off = 32; off >= 1; off >>= 1) {
        v0 += __shfl_down(v0, off);
        v1 += __shfl_down(v1, off);
        v2 += __shfl_down(v2, off);
    }
    if ((tid & 63) == 0) { s_sum[tid >> 6][0] = v0; s_sum[tid >> 6][1] = v1; s_sum[tid >> 6][2] = v2; }
    __syncthreads();
    if (tid == 0) {
        out[3] = (float)(s_sum[0][0] + s_sum[1][0] + s_sum[2][0] + s_sum[3][0]);
        out[4] = (float)(s_sum[0][1] + s_sum[1][1] + s_sum[2][1] + s_sum[3][1]);
        out[5] = (float)(s_sum[0][2] + s_sum[1][2] + s_sum[2][2] + s_sum[3][2]);
        const float rq    = 1.25f * acc[0] / ((float)N_ROWS * 128.0f);
        const float recon =         acc[1] / ((float)N_ROWS * 512.0f);
        out[0] = recon + rq;
        out[1] = recon;
        out[2] = rq;
    }
}

extern "C" void kernel_launch(void* const* d_in, const int* in_sizes, int n_in,
                              void* d_out, int out_size, void* d_ws, size_t ws_size,
                              hipStream_t stream) {
    const float* emb  = (const float*)d_in[0];
    const float* Wenc = (const float*)d_in[1];
    const float* Wdec = (const float*)d_in[2];
    const float* cb0  = (const float*)d_in[3];
    const float* cb1  = (const float*)d_in[4];
    const float* cb2  = (const float*)d_in[5];

    // workspace layout (bytes): [0] 2 f32 acc | [64] 768 int used | [3200] 768 f32 norms | [8192] 448KB bf16 frags
    float* ws_f  = (float*)d_ws;
    int*   used  = (int*)((char*)d_ws + 64);
    float* norms = (float*)((char*)d_ws + 3200);
    unsigned short* wsb = (unsigned short*)((char*)d_ws + 8192);

    rqvae_prep<<<115, NT, 0, stream>>>(Wenc, Wdec, cb0, cb1, cb2, wsb, norms, ws_f);
    rqvae_main<<<NBLK, NT, 0, stream>>>(emb, cb0, cb1, cb2, wsb, norms,
                                        ws_f + 0, ws_f + 1, used);
    rqvae_finalize<<<1, NT, 0, stream>>>(ws_f, used, (float*)d_out);
}